// Round 11
// baseline (317.342 us; speedup 1.0000x reference)
//
#include <hip/hip_runtime.h>
#include <math.h>

#define NB 16
#define NC 64
#define HW 160
#define PLANE (HW * HW)               // 25600
#define SG 161                        // site grid (H+1)
#define SGSQ (SG * SG)                // 25921
#define NSITES (NB * SGSQ)            // 414736
#define OUT_LD_OFF (NB * NC * PLANE)  // logdet output offset
#define TILE 256                      // sites per conv block
#define NCONV ((NSITES + TILE - 1) / TILE)  // 1621

// Det-block LDS (conv blocks use none):
//   phase 1: A64 with LD=65 -> 4160 floats
//   phase 2 overlay: wave1 2x(32x33)@0,1056 | wave2 @2112,3168 |
//                    wave3 4x(16x17)@4224+g*272
//   partial[4] @5312, pivslot @5316. 21.3 KB.
#define SMEM_FLOATS 5320

// Map local submatrix index -> channel index for the INDS masks.
__device__ inline int chmap(int i, int n, int pa, int pb) {
    if (n == 64) return i;
    if (n == 32) return ((i >> 1) << 2) | ((i & 1) ? pb : pa);
    return (i << 2) | pa;
}

// Single-wave-group LDS LU (N=32/16), stride N+1, x4-batched row updates.
template <int N>
__device__ float group_lu_logabsdet(const float* __restrict__ W, float* A,
                                    int pa, int pb, int lane) {
    const int r = lane & (N - 1);  // row during pivot; column during update
    constexpr int LD = N + 1;
#pragma unroll 4
    for (int i = 0; i < N; ++i)
        A[i * LD + r] = W[chmap(i, N, pa, pb) * 64 + chmap(r, N, pa, pb)];
    asm volatile("s_waitcnt lgkmcnt(0) vmcnt(0)" ::: "memory");
    float logdet = 0.f;
    for (int k = 0; k < N; ++k) {
        float cand = (r >= k) ? fabsf(A[r * LD + k]) : -1.f;
        int idx = r;
#pragma unroll
        for (int off = N >> 1; off; off >>= 1) {
            float oc = __shfl_xor(cand, off, N);
            int oi = __shfl_xor(idx, off, N);
            if (oc > cand || (oc == cand && oi < idx)) { cand = oc; idx = oi; }
        }
        const int p = idx;  // uniform within group
        if (p != k) {
            float tk = A[k * LD + r];
            float tp = A[p * LD + r];
            A[k * LD + r] = tp;
            A[p * LD + r] = tk;
        }
        asm volatile("s_waitcnt lgkmcnt(0)" ::: "memory");
        float piv = A[k * LD + k];
        logdet += logf(fabsf(piv));
        float rpiv = 1.f / piv;
        if (r > k) {
            float wk = A[k * LD + r] * rpiv;
            int i = k + 1;
            for (; i + 3 < N; i += 4) {
                float a0 = A[(i + 0) * LD + k], a1 = A[(i + 1) * LD + k],
                      a2 = A[(i + 2) * LD + k], a3 = A[(i + 3) * LD + k];
                float x0 = A[(i + 0) * LD + r], x1 = A[(i + 1) * LD + r],
                      x2 = A[(i + 2) * LD + r], x3 = A[(i + 3) * LD + r];
                A[(i + 0) * LD + r] = fmaf(-a0, wk, x0);
                A[(i + 1) * LD + r] = fmaf(-a1, wk, x1);
                A[(i + 2) * LD + r] = fmaf(-a2, wk, x2);
                A[(i + 3) * LD + r] = fmaf(-a3, wk, x3);
            }
            for (; i < N; ++i) {
                float a0 = A[i * LD + k], x0 = A[i * LD + r];
                A[i * LD + r] = fmaf(-a0, wk, x0);
            }
        }
        asm volatile("s_waitcnt lgkmcnt(0)" ::: "memory");
    }
    return logdet;  // identical across the N-lane group
}

// ---------------- conv macros (round-8 shape: u[32], no spill) ----------------
// Thread = site. Per output-half: 4 k-chunks of 16; unconditional CLAMPED
// loads (mask multiplied after return); 2-deep chunk pipeline va/vb.
// Second half re-reads the SAME 64 x addresses -> same-CU L1/L2 hits.
#define LOADCH(dst, cc)                                                      \
    {                                                                        \
        _Pragma("unroll") for (int i = 0; i < 16; ++i)                       \
            dst[i] = xb[(size_t)((((cc) << 4) + (i ^ 3)) * PLANE) +          \
                        aoff[i & 3]];                                        \
    }

#define COMPCH(src, cc)                                                      \
    {                                                                        \
        _Pragma("unroll") for (int i = 0; i < 16; ++i) src[i] *= mf[i & 3];  \
        _Pragma("unroll") for (int j = 0; j < 32; ++j) {                     \
            const float* wr = wbase + j * 64 + ((cc) << 4);                  \
            float4 w0 = *(const float4*)(wr + 0);                            \
            float4 w1 = *(const float4*)(wr + 4);                            \
            float4 w2 = *(const float4*)(wr + 8);                            \
            float4 w3 = *(const float4*)(wr + 12);                           \
            float a = u[j];                                                  \
            a = fmaf(w0.x, src[0], a);  a = fmaf(w0.y, src[1], a);           \
            a = fmaf(w0.z, src[2], a);  a = fmaf(w0.w, src[3], a);           \
            a = fmaf(w1.x, src[4], a);  a = fmaf(w1.y, src[5], a);           \
            a = fmaf(w1.z, src[6], a);  a = fmaf(w1.w, src[7], a);           \
            a = fmaf(w2.x, src[8], a);  a = fmaf(w2.y, src[9], a);           \
            a = fmaf(w2.z, src[10], a); a = fmaf(w2.w, src[11], a);          \
            a = fmaf(w3.x, src[12], a); a = fmaf(w3.y, src[13], a);          \
            a = fmaf(w3.z, src[14], a); a = fmaf(w3.w, src[15], a);          \
            u[j] = a;                                                        \
        }                                                                    \
    }

__global__ __launch_bounds__(256, 5) void InvConv1x1GridAlign_kernel(
    const float* __restrict__ x, const float* __restrict__ ld_in,
    const float* __restrict__ W, float* __restrict__ out) {
    __shared__ __align__(16) float smem[SMEM_FLOATS];
    const int tid = threadIdx.x;

    if (blockIdx.x == 0) {
        // ---- det block: coop 64-LU (all 4 waves), then parallel 32s/16s ----
        float* A = smem;
        float* partial = smem + 5312;
        float* pivslot = smem + 5316;
        const int lane = tid & 63;
        const int wid = tid >> 6;
        for (int e = tid; e < 64 * 64; e += 256)
            A[(e >> 6) * 65 + (e & 63)] = W[e];
        __syncthreads();
        float logdet64 = 0.f;
        for (int k = 0; k < 64; ++k) {
            if (wid == 0) {  // pivot (lane=row) + swap (lane=column)
                float cand = (lane >= k) ? fabsf(A[lane * 65 + k]) : -1.f;
                int idx = lane;
#pragma unroll
                for (int off = 32; off; off >>= 1) {
                    float oc = __shfl_xor(cand, off, 64);
                    int oi = __shfl_xor(idx, off, 64);
                    if (oc > cand || (oc == cand && oi < idx)) {
                        cand = oc;
                        idx = oi;
                    }
                }
                const int p = idx;
                if (p != k) {
                    float tk = A[k * 65 + lane];
                    float tp = A[p * 65 + lane];
                    A[k * 65 + lane] = tp;
                    A[p * 65 + lane] = tk;
                }
                asm volatile("s_waitcnt lgkmcnt(0)" ::: "memory");
                if (lane == 0) pivslot[0] = A[k * 65 + k];
            }
            __syncthreads();
            const float piv = pivslot[0];
            logdet64 += logf(fabsf(piv));
            const float rpiv = 1.f / piv;
            const float akr = A[k * 65 + lane];  // row-k entry, this column
            int i = k + 1 + wid;  // wave w owns rows ≡ k+1+w (mod 4)
            for (; i + 12 < 64; i += 16) {
                float a0 = A[(i + 0) * 65 + k], a1 = A[(i + 4) * 65 + k],
                      a2 = A[(i + 8) * 65 + k], a3 = A[(i + 12) * 65 + k];
                float x0 = A[(i + 0) * 65 + lane], x1 = A[(i + 4) * 65 + lane],
                      x2 = A[(i + 8) * 65 + lane], x3 = A[(i + 12) * 65 + lane];
                A[(i + 0) * 65 + lane] = fmaf(-(a0 * rpiv), akr, x0);
                A[(i + 4) * 65 + lane] = fmaf(-(a1 * rpiv), akr, x1);
                A[(i + 8) * 65 + lane] = fmaf(-(a2 * rpiv), akr, x2);
                A[(i + 12) * 65 + lane] = fmaf(-(a3 * rpiv), akr, x3);
            }
            for (; i < 64; i += 4) {
                float a0 = A[i * 65 + k];
                A[i * 65 + lane] = fmaf(-(a0 * rpiv), akr, A[i * 65 + lane]);
            }
            asm volatile("s_waitcnt lgkmcnt(0)" ::: "memory");
            __syncthreads();
        }
        if (tid == 0) partial[0] = 25281.f * logdet64;  // (159*159)
        __syncthreads();  // frees A for the phase-2 overlay
        if (wid == 1) {
            int g = lane >> 5;  // t: {2,3} || b: {0,1}
            float ld = group_lu_logabsdet<32>(W, A + g * 1056, g ? 0 : 2,
                                              g ? 1 : 3, lane);
            float part = (__shfl(ld, 0, 64) + __shfl(ld, 32, 64)) * 159.f;
            if (lane == 0) partial[1] = part;
        } else if (wid == 2) {
            int g = lane >> 5;  // l: {1,3} || r: {0,2}
            float ld = group_lu_logabsdet<32>(W, A + 2112 + g * 1056,
                                              g ? 0 : 1, g ? 2 : 3, lane);
            float part = (__shfl(ld, 0, 64) + __shfl(ld, 32, 64)) * 159.f;
            if (lane == 0) partial[2] = part;
        } else if (wid == 3) {
            int g = lane >> 4;  // tl:{3} tr:{2} bl:{1} br:{0}
            float ld = group_lu_logabsdet<16>(W, A + 4224 + g * 272, 3 - g, 0,
                                              lane);
            float part = __shfl(ld, 0, 64) + __shfl(ld, 16, 64) +
                         __shfl(ld, 32, 64) + __shfl(ld, 48, 64);
            if (lane == 0) partial[3] = part;
        }
        __syncthreads();
        if (tid < NB) {
            float dl = partial[0] + partial[1] + partial[2] + partial[3];
            out[OUT_LD_OFF + tid] = ld_in[tid] + dl;
        }
        return;
    }

    // ---- conv blocks: thread = site; TWO passes of 32 outputs each.
    // Pass 2 re-reads the identical x addresses -> L1/L2 hits (no HBM dup).
    const int s = ((int)blockIdx.x - 1) * TILE + tid;

    const int offm[4] = {0, 1, HW, HW + 1};
    bool vm[4];
    int aoff[4];
    float mf[4];
    int baseoff;
    const float* xb;
    float* ob;
    {
        bool sok = s < NSITES;
        unsigned us = (unsigned)(sok ? s : 0);
        unsigned b = us / SGSQ;
        unsigned rr = us - b * SGSQ;
        unsigned Y = rr / SG;
        unsigned X = rr - Y * SG;
        xb = x + (size_t)b * (NC * PLANE);
        ob = out + (size_t)b * (NC * PLANE);
        baseoff = ((int)Y - 1) * HW + ((int)X - 1);
        bool okT = sok && (Y >= 1), okB = sok && (Y <= HW - 1);
        bool okL = (X >= 1), okR = (X <= HW - 1);
        vm[0] = okT && okL; vm[1] = okT && okR;
        vm[2] = okB && okL; vm[3] = okB && okR;
#pragma unroll
        for (int m = 0; m < 4; ++m) {
            aoff[m] = vm[m] ? (baseoff + offm[m]) : 0;  // clamped in-bounds
            mf[m] = vm[m] ? 1.f : 0.f;
        }
    }

    float u[32];
    float va[16], vb[16];
#pragma unroll 1
    for (int oh = 0; oh < 2; ++oh) {
        const float* wbase = W + ((oh << 5) * 64);
#pragma unroll
        for (int j = 0; j < 32; ++j) u[j] = 0.f;

        LOADCH(va, 0)
#pragma unroll 1
        for (int cc = 0; cc < 4; cc += 2) {
            LOADCH(vb, cc + 1)
            COMPCH(va, cc)
            if (cc + 2 < 4) LOADCH(va, cc + 2)
            COMPCH(vb, cc + 1)
        }

        // stores grouped by quadrant: one exec toggle per 8 coalesced stores
#pragma unroll
        for (int m = 0; m < 4; ++m) {
            if (vm[m]) {
#pragma unroll
                for (int t = 0; t < 8; ++t) {
                    int j = (t << 2) + m;  // j&3 == m
                    ob[(size_t)(((oh << 5) + (j ^ 3)) * PLANE) + baseoff +
                       offm[m]] = u[j];
                }
            }
        }
    }
}

extern "C" void kernel_launch(void* const* d_in, const int* in_sizes, int n_in,
                              void* d_out, int out_size, void* d_ws, size_t ws_size,
                              hipStream_t stream) {
    const float* x = (const float*)d_in[0];
    const float* ld = (const float*)d_in[1];
    const float* W = (const float*)d_in[2];
    float* out = (float*)d_out;
    hipLaunchKernelGGL(InvConv1x1GridAlign_kernel, dim3(NCONV + 1), dim3(256),
                       0, stream, x, ld, W, out);
}

// Round 12
// 240.774 us; speedup vs baseline: 1.3180x; 1.3180x over previous
//
#include <hip/hip_runtime.h>
#include <math.h>

#define NB 16
#define NC 64
#define HW 160
#define PLANE (HW * HW)               // 25600
#define SG 161                        // site grid (H+1)
#define SGSQ (SG * SG)                // 25921
#define NSITES (NB * SGSQ)            // 414736
#define OUT_LD_OFF (NB * NC * PLANE)  // logdet output offset
#define TILE 256                      // sites per conv block
#define NCONV ((NSITES + TILE - 1) / TILE)  // 1621

// Det-block LDS (conv blocks use none):
//   phase 1: A64 with LD=65 -> 4160 floats (wave 0 only, barrier-free)
//   phase 2 overlay (after one barrier): wave1 2x(32x33)@0,1056 |
//     wave2 @2112,3168 | wave3 4x(16x17)@4224+g*272 -> 5312
//   partial[4] @5312. 21.3 KB -> 5 blocks/CU preserved.
#define SMEM_FLOATS 5320

// Map local submatrix index -> channel index for the INDS masks.
__device__ inline int chmap(int i, int n, int pa, int pb) {
    if (n == 64) return i;
    if (n == 32) return ((i >> 1) << 2) | ((i & 1) ? pb : pa);
    return (i << 2) | pa;
}

// Single-wave-group LDS LU (N=32/16), stride N+1, x4-batched row updates.
template <int N>
__device__ float group_lu_logabsdet(const float* __restrict__ W, float* A,
                                    int pa, int pb, int lane) {
    const int r = lane & (N - 1);  // row during pivot; column during update
    constexpr int LD = N + 1;
#pragma unroll 4
    for (int i = 0; i < N; ++i)
        A[i * LD + r] = W[chmap(i, N, pa, pb) * 64 + chmap(r, N, pa, pb)];
    asm volatile("s_waitcnt lgkmcnt(0) vmcnt(0)" ::: "memory");
    float logdet = 0.f;
    for (int k = 0; k < N; ++k) {
        float cand = (r >= k) ? fabsf(A[r * LD + k]) : -1.f;
        int idx = r;
#pragma unroll
        for (int off = N >> 1; off; off >>= 1) {
            float oc = __shfl_xor(cand, off, N);
            int oi = __shfl_xor(idx, off, N);
            if (oc > cand || (oc == cand && oi < idx)) { cand = oc; idx = oi; }
        }
        const int p = idx;  // uniform within group
        if (p != k) {
            float tk = A[k * LD + r];
            float tp = A[p * LD + r];
            A[k * LD + r] = tp;
            A[p * LD + r] = tk;
        }
        asm volatile("s_waitcnt lgkmcnt(0)" ::: "memory");
        float piv = A[k * LD + k];
        logdet += logf(fabsf(piv));
        float rpiv = 1.f / piv;
        if (r > k) {
            float wk = A[k * LD + r] * rpiv;
            int i = k + 1;
            for (; i + 3 < N; i += 4) {
                float a0 = A[(i + 0) * LD + k], a1 = A[(i + 1) * LD + k],
                      a2 = A[(i + 2) * LD + k], a3 = A[(i + 3) * LD + k];
                float x0 = A[(i + 0) * LD + r], x1 = A[(i + 1) * LD + r],
                      x2 = A[(i + 2) * LD + r], x3 = A[(i + 3) * LD + r];
                A[(i + 0) * LD + r] = fmaf(-a0, wk, x0);
                A[(i + 1) * LD + r] = fmaf(-a1, wk, x1);
                A[(i + 2) * LD + r] = fmaf(-a2, wk, x2);
                A[(i + 3) * LD + r] = fmaf(-a3, wk, x3);
            }
            for (; i < N; ++i) {
                float a0 = A[i * LD + k], x0 = A[i * LD + r];
                A[i * LD + r] = fmaf(-a0, wk, x0);
            }
        }
        asm volatile("s_waitcnt lgkmcnt(0)" ::: "memory");
    }
    return logdet;  // identical across the N-lane group
}

// ---------------- conv macros (round-8/9 shape: u[32], straight-line) -------
#define LOADCH(dst, cc)                                                      \
    {                                                                        \
        _Pragma("unroll") for (int i = 0; i < 16; ++i)                       \
            dst[i] = xb[(size_t)(((cc) << 4) + (i ^ 3)) * PLANE +            \
                        aoff[i & 3]];                                        \
    }

#define COMPCH(src, cc)                                                      \
    {                                                                        \
        _Pragma("unroll") for (int i = 0; i < 16; ++i) src[i] *= mf[i & 3];  \
        _Pragma("unroll") for (int j = 0; j < 32; ++j) {                     \
            const float* wr = wbase + j * 64 + ((cc) << 4);                  \
            float4 w0 = *(const float4*)(wr + 0);                            \
            float4 w1 = *(const float4*)(wr + 4);                            \
            float4 w2 = *(const float4*)(wr + 8);                            \
            float4 w3 = *(const float4*)(wr + 12);                           \
            float a = u[j];                                                  \
            a = fmaf(w0.x, src[0], a);  a = fmaf(w0.y, src[1], a);           \
            a = fmaf(w0.z, src[2], a);  a = fmaf(w0.w, src[3], a);           \
            a = fmaf(w1.x, src[4], a);  a = fmaf(w1.y, src[5], a);           \
            a = fmaf(w1.z, src[6], a);  a = fmaf(w1.w, src[7], a);           \
            a = fmaf(w2.x, src[8], a);  a = fmaf(w2.y, src[9], a);           \
            a = fmaf(w2.z, src[10], a); a = fmaf(w2.w, src[11], a);          \
            a = fmaf(w3.x, src[12], a); a = fmaf(w3.y, src[13], a);          \
            a = fmaf(w3.z, src[14], a); a = fmaf(w3.w, src[15], a);          \
            u[j] = a;                                                        \
        }                                                                    \
    }

__global__ __launch_bounds__(256, 5) void InvConv1x1GridAlign_kernel(
    const float* __restrict__ x, const float* __restrict__ ld_in,
    const float* __restrict__ W, float* __restrict__ out) {
    __shared__ __align__(16) float smem[SMEM_FLOATS];
    const int tid = threadIdx.x;

    if (blockIdx.x == 0) {
        // ---- det block ----
        float* A = smem;
        float* partial = smem + 5312;
        const int lane = tid & 63;
        const int wid = tid >> 6;

        if (wid == 0) {
            // Barrier-free blocked LU (8-col panels in registers, lane=row).
            const int r = lane;
            for (int e = lane; e < 64 * 64; e += 64)
                A[(e >> 6) * 65 + (e & 63)] = W[e];
            asm volatile("s_waitcnt lgkmcnt(0) vmcnt(0)" ::: "memory");
            float ll = 0.f;
#pragma unroll 1
            for (int p8 = 0; p8 < 8; ++p8) {
                const int k0 = p8 << 3;
                float a[8];
#pragma unroll
                for (int c = 0; c < 8; ++c) a[c] = A[r * 65 + k0 + c];
                int pivs[8];
                // -- panel factorization, all in registers/shuffles --
#pragma unroll
                for (int t = 0; t < 8; ++t) {
                    const int k = k0 + t;
                    float cand = (r >= k) ? fabsf(a[t]) : -1.f;
                    int idx = r;
#pragma unroll
                    for (int off = 32; off; off >>= 1) {
                        float oc = __shfl_xor(cand, off, 64);
                        int oi = __shfl_xor(idx, off, 64);
                        if (oc > cand || (oc == cand && oi < idx)) {
                            cand = oc;
                            idx = oi;
                        }
                    }
                    const int prow = idx;  // uniform
                    float apk = __shfl(a[t], prow, 64);
                    ll += logf(fabsf(apk));
                    float rpiv = 1.f / apk;
                    pivs[t] = prow;
                    // swap lanes k <-> prow across the 8 panel regs
#pragma unroll
                    for (int c = 0; c < 8; ++c) {
                        float vk = __shfl(a[c], k, 64);
                        float vp = __shfl(a[c], prow, 64);
                        a[c] = (r == k) ? vp : ((r == prow) ? vk : a[c]);
                    }
                    if (r > k) a[t] *= rpiv;  // multipliers
#pragma unroll
                    for (int c = t + 1; c < 8; ++c) {
                        float ukc = __shfl(a[c], k, 64);  // U[k][k0+c]
                        if (r > k) a[c] = fmaf(-a[t], ukc, a[c]);
                    }
                }
#pragma unroll
                for (int c = 0; c < 8; ++c) A[r * 65 + k0 + c] = a[c];
                asm volatile("s_waitcnt lgkmcnt(0)" ::: "memory");
                const int ncols = 64 - k0 - 8;
                if (ncols > 0) {
                    const int j = k0 + 8 + r;  // this lane's trailing col
                    const bool jok = r < ncols;
                    // deferred row swaps on trailing cols only (L-part is
                    // det-irrelevant); per-lane col => in-order per thread
#pragma unroll
                    for (int t = 0; t < 8; ++t) {
                        const int k = k0 + t, p_ = pivs[t];
                        if (p_ != k && jok) {
                            float hk = A[k * 65 + j];
                            float hp = A[p_ * 65 + j];
                            A[k * 65 + j] = hp;
                            A[p_ * 65 + j] = hk;
                        }
                    }
                    // U12 solve: rows k0..k0+7, this lane's col, u in regs
                    float u[8];
#pragma unroll
                    for (int t = 0; t < 8; ++t)
                        u[t] = jok ? A[(k0 + t) * 65 + j] : 0.f;
#pragma unroll
                    for (int t = 1; t < 8; ++t)
#pragma unroll
                        for (int s2 = 0; s2 < t; ++s2) {
                            float lts = A[(k0 + t) * 65 + k0 + s2];  // bcast
                            u[t] = fmaf(-lts, u[s2], u[t]);
                        }
                    if (jok) {
#pragma unroll
                        for (int t = 1; t < 8; ++t) A[(k0 + t) * 65 + j] = u[t];
                    }
                    // rank-8 trailing update; U stays in regs (u[t])
#pragma unroll 4
                    for (int i = k0 + 8; i < 64; ++i) {
                        float acc2 = jok ? A[i * 65 + j] : 0.f;
#pragma unroll
                        for (int t = 0; t < 8; ++t) {
                            float lit = A[i * 65 + k0 + t];  // bcast
                            acc2 = fmaf(-lit, u[t], acc2);
                        }
                        if (jok) A[i * 65 + j] = acc2;
                    }
                    asm volatile("s_waitcnt lgkmcnt(0)" ::: "memory");
                }
            }
            if (lane == 0) partial[0] = 25281.f * ll;  // (159*159)
        }
        __syncthreads();  // A64 dead; overlay free for small dets
        if (wid == 1) {
            int g = lane >> 5;  // t: {2,3} || b: {0,1}
            float ld = group_lu_logabsdet<32>(W, A + g * 1056, g ? 0 : 2,
                                              g ? 1 : 3, lane);
            float part = (__shfl(ld, 0, 64) + __shfl(ld, 32, 64)) * 159.f;
            if (lane == 0) partial[1] = part;
        } else if (wid == 2) {
            int g = lane >> 5;  // l: {1,3} || r: {0,2}
            float ld = group_lu_logabsdet<32>(W, A + 2112 + g * 1056,
                                              g ? 0 : 1, g ? 2 : 3, lane);
            float part = (__shfl(ld, 0, 64) + __shfl(ld, 32, 64)) * 159.f;
            if (lane == 0) partial[2] = part;
        } else if (wid == 3) {
            int g = lane >> 4;  // tl:{3} tr:{2} bl:{1} br:{0}
            float ld = group_lu_logabsdet<16>(W, A + 4224 + g * 272, 3 - g, 0,
                                              lane);
            float part = __shfl(ld, 0, 64) + __shfl(ld, 16, 64) +
                         __shfl(ld, 32, 64) + __shfl(ld, 48, 64);
            if (lane == 0) partial[3] = part;
        }
        __syncthreads();
        if (tid < NB) {
            float dl = partial[0] + partial[1] + partial[2] + partial[3];
            out[OUT_LD_OFF + tid] = ld_in[tid] + dl;
        }
        return;
    }

    // ---- conv blocks (round-8/9 verified form, verbatim) ----
    const int cbid = (int)blockIdx.x - 1;
    const int ohalf = cbid & 1;              // which 32 outputs
    const int s = (cbid >> 1) * TILE + tid;  // site index

    const int offm[4] = {0, 1, HW, HW + 1};
    bool vm[4];
    int aoff[4];
    float mf[4];
    int baseoff;
    const float* xb;
    float* ob;
    {
        bool sok = s < NSITES;
        unsigned us = (unsigned)(sok ? s : 0);
        unsigned b = us / SGSQ;
        unsigned rr = us - b * SGSQ;
        unsigned Y = rr / SG;
        unsigned X = rr - Y * SG;
        xb = x + (size_t)b * (NC * PLANE);
        ob = out + (size_t)b * (NC * PLANE);
        baseoff = ((int)Y - 1) * HW + ((int)X - 1);
        bool okT = sok && (Y >= 1), okB = sok && (Y <= HW - 1);
        bool okL = (X >= 1), okR = (X <= HW - 1);
        vm[0] = okT && okL; vm[1] = okT && okR;
        vm[2] = okB && okL; vm[3] = okB && okR;
#pragma unroll
        for (int m = 0; m < 4; ++m) {
            aoff[m] = vm[m] ? (baseoff + offm[m]) : 0;  // clamped in-bounds
            mf[m] = vm[m] ? 1.f : 0.f;
        }
    }

    const float* wbase = W + (ohalf << 5) * 64;

    float u[32];
#pragma unroll
    for (int j = 0; j < 32; ++j) u[j] = 0.f;

    float va[16], vb[16];
    LOADCH(va, 0)
    LOADCH(vb, 1)
    COMPCH(va, 0)
    LOADCH(va, 2)
    COMPCH(vb, 1)
    LOADCH(vb, 3)
    COMPCH(va, 2)
    COMPCH(vb, 3)

    // stores grouped by quadrant: one exec toggle per 8 coalesced stores
#pragma unroll
    for (int m = 0; m < 4; ++m) {
        if (vm[m]) {
#pragma unroll
            for (int t = 0; t < 8; ++t) {
                int j = (t << 2) + m;  // j&3 == m
                ob[(size_t)((ohalf << 5) + (j ^ 3)) * PLANE + baseoff +
                   offm[m]] = u[j];
            }
        }
    }
}

extern "C" void kernel_launch(void* const* d_in, const int* in_sizes, int n_in,
                              void* d_out, int out_size, void* d_ws, size_t ws_size,
                              hipStream_t stream) {
    const float* x = (const float*)d_in[0];
    const float* ld = (const float*)d_in[1];
    const float* W = (const float*)d_in[2];
    float* out = (float*)d_out;
    hipLaunchKernelGGL(InvConv1x1GridAlign_kernel, dim3(2 * NCONV + 1),
                       dim3(256), 0, stream, x, ld, W, out);
}